// Round 1
// baseline (178.194 us; speedup 1.0000x reference)
//
#include <hip/hip_runtime.h>

// KirchhoffNet: per-edge gated current + signed scatter into nodes.
// out[n] = sum_{e: dst==n} cur[e] - sum_{e: src==n} cur[e]
// cur[e] = cond[e] * relu(t1[e]*(v[src]-v[dst]) + t2[e])

__global__ __launch_bounds__(256) void kirchhoff_edge_kernel(
    const float* __restrict__ v,
    const int*   __restrict__ src,
    const int*   __restrict__ dst,
    const float* __restrict__ t1,
    const float* __restrict__ t2,
    const float* __restrict__ cond,
    float*       __restrict__ out,
    int E)
{
    int i = blockIdx.x * blockDim.x + threadIdx.x;
    int stride = gridDim.x * blockDim.x;
    for (; i < E; i += stride) {
        int s = src[i];
        int d = dst[i];
        float diff = v[s] - v[d];
        float x = fmaf(t1[i], diff, t2[i]);
        if (x > 0.0f) {
            float cur = cond[i] * x;
            atomicAdd(&out[d],  cur);
            atomicAdd(&out[s], -cur);
        }
    }
}

extern "C" void kernel_launch(void* const* d_in, const int* in_sizes, int n_in,
                              void* d_out, int out_size, void* d_ws, size_t ws_size,
                              hipStream_t stream) {
    // setup_inputs order: t(0), v(1), src(2), dst(3), theta_sd_1(4), theta_sd_2(5), conductance(6)
    const float* v    = (const float*)d_in[1];
    const int*   src  = (const int*)  d_in[2];
    const int*   dst  = (const int*)  d_in[3];
    const float* t1   = (const float*)d_in[4];
    const float* t2   = (const float*)d_in[5];
    const float* cond = (const float*)d_in[6];
    float* out = (float*)d_out;
    const int E = in_sizes[2];

    // d_out is poisoned (0xAA) before timing and NOT re-zeroed between replays:
    // zero it ourselves every call (graph-capture-safe async memset).
    hipMemsetAsync(d_out, 0, (size_t)out_size * sizeof(float), stream);

    const int block = 256;
    int grid = (E + block - 1) / block;
    if (grid > 2048) grid = 2048;  // grid-stride; memory-bound cap per G11
    kirchhoff_edge_kernel<<<grid, block, 0, stream>>>(v, src, dst, t1, t2, cond, out, E);
}

// Round 2
// 173.651 us; speedup vs baseline: 1.0262x; 1.0262x over previous
//
#include <hip/hip_runtime.h>

// KirchhoffNet: per-edge gated current + signed scatter into nodes.
// out[n] = sum_{e: dst==n} cur[e] - sum_{e: src==n} cur[e]
// cur[e] = cond[e] * relu(t1[e]*(v[src]-v[dst]) + t2[e])
//
// Round 2: privatize the atomic target into P=8 copies (one per XCD via
// blockIdx&7 round-robin dispatch) to cut per-cacheline atomic contention,
// then reduce the copies. Vectorize edge streams x4.

__global__ __launch_bounds__(256) void kirchhoff_edge_kernel(
    const float* __restrict__ v,
    const int*   __restrict__ src,
    const int*   __restrict__ dst,
    const float* __restrict__ t1,
    const float* __restrict__ t2,
    const float* __restrict__ cond,
    float*       __restrict__ partial,   // [P][N]
    int N, int E, int pmask)             // pmask = P-1, P power of two
{
    float* my = partial + (size_t)(blockIdx.x & pmask) * N;

    const int E4 = E & ~3;
    int chunk = blockIdx.x * blockDim.x + threadIdx.x;   // one 4-edge chunk per thread
    int nthreads = gridDim.x * blockDim.x;

    for (int i = chunk * 4; i + 3 < E4; i += nthreads * 4) {
        int4   s4 = *(const int4*)  (src  + i);
        int4   d4 = *(const int4*)  (dst  + i);
        float4 a4 = *(const float4*)(t1   + i);
        float4 b4 = *(const float4*)(t2   + i);
        float4 c4 = *(const float4*)(cond + i);

        float x0 = fmaf(a4.x, v[s4.x] - v[d4.x], b4.x);
        float x1 = fmaf(a4.y, v[s4.y] - v[d4.y], b4.y);
        float x2 = fmaf(a4.z, v[s4.z] - v[d4.z], b4.z);
        float x3 = fmaf(a4.w, v[s4.w] - v[d4.w], b4.w);

        if (x0 > 0.0f) { float c = c4.x * x0; atomicAdd(&my[d4.x],  c); atomicAdd(&my[s4.x], -c); }
        if (x1 > 0.0f) { float c = c4.y * x1; atomicAdd(&my[d4.y],  c); atomicAdd(&my[s4.y], -c); }
        if (x2 > 0.0f) { float c = c4.z * x2; atomicAdd(&my[d4.z],  c); atomicAdd(&my[s4.z], -c); }
        if (x3 > 0.0f) { float c = c4.w * x3; atomicAdd(&my[d4.w],  c); atomicAdd(&my[s4.w], -c); }
    }

    // scalar tail (E not divisible by 4)
    for (int i = E4 + chunk; i < E; i += nthreads) {
        int s = src[i], d = dst[i];
        float x = fmaf(t1[i], v[s] - v[d], t2[i]);
        if (x > 0.0f) { float c = cond[i] * x; atomicAdd(&my[d], c); atomicAdd(&my[s], -c); }
    }
}

__global__ __launch_bounds__(256) void kirchhoff_reduce_kernel(
    const float* __restrict__ partial, float* __restrict__ out, int N, int P)
{
    int n = blockIdx.x * blockDim.x + threadIdx.x;
    if (n < N) {
        float s = 0.0f;
        for (int p = 0; p < P; ++p) s += partial[(size_t)p * N + n];
        out[n] = s;
    }
}

extern "C" void kernel_launch(void* const* d_in, const int* in_sizes, int n_in,
                              void* d_out, int out_size, void* d_ws, size_t ws_size,
                              hipStream_t stream) {
    // setup_inputs order: t(0), v(1), src(2), dst(3), theta_sd_1(4), theta_sd_2(5), conductance(6)
    const float* v    = (const float*)d_in[1];
    const int*   src  = (const int*)  d_in[2];
    const int*   dst  = (const int*)  d_in[3];
    const float* t1   = (const float*)d_in[4];
    const float* t2   = (const float*)d_in[5];
    const float* cond = (const float*)d_in[6];
    float* out = (float*)d_out;
    const int E = in_sizes[2];
    const int N = out_size;

    // Pick largest power-of-two P (<=8) of [N] float copies that fits in ws.
    int P = 0;
    size_t per = (size_t)N * sizeof(float);
    if      (ws_size >= 8 * per) P = 8;
    else if (ws_size >= 4 * per) P = 4;
    else if (ws_size >= 2 * per) P = 2;
    else if (ws_size >= 1 * per) P = 1;

    float* partial = (P > 0) ? (float*)d_ws : out;
    int    Puse    = (P > 0) ? P : 1;

    hipMemsetAsync(partial, 0, (size_t)Puse * per, stream);

    const int block = 256;
    int chunks = (E + 3) / 4;
    int grid = (chunks + block - 1) / block;   // exact cover: 1 chunk per thread
    kirchhoff_edge_kernel<<<grid, block, 0, stream>>>(v, src, dst, t1, t2, cond,
                                                      partial, N, E, Puse - 1);

    if (P > 0) {
        int rgrid = (N + block - 1) / block;
        kirchhoff_reduce_kernel<<<rgrid, block, 0, stream>>>(partial, out, N, Puse);
    }
}

// Round 3
// 172.801 us; speedup vs baseline: 1.0312x; 1.0049x over previous
//
#include <hip/hip_runtime.h>

// KirchhoffNet: out[n] = sum_{dst==n} cur - sum_{src==n} cur,
// cur = cond * relu(t1*(v[src]-v[dst]) + t2)
//
// Round 3: agent-scope fp atomics execute memory-side on gfx950 (observed
// ~32B EA write per atomic, 100MB WRITE_SIZE). Switch to WORKGROUP-scope
// relaxed fetch_add -> RMW executes in the XCD-local L2. Correct only if
// each partial copy is touched by exactly one XCD -> privatize by the REAL
// XCC_ID (s_getreg HW_REG_XCC_ID, 0..7). Reduce the 8 copies afterwards
// (kernel-boundary release flushes dirty L2 lines).

__device__ __forceinline__ unsigned xcc_id() {
    unsigned x;
    asm volatile("s_getreg_b32 %0, hwreg(HW_REG_XCC_ID)" : "=s"(x));
    return x & 7u;
}

__device__ __forceinline__ void atom_add_local(float* p, float v) {
    __hip_atomic_fetch_add(p, v, __ATOMIC_RELAXED, __HIP_MEMORY_SCOPE_WORKGROUP);
}

template <bool PRIV>
__global__ __launch_bounds__(256) void kirchhoff_edge_kernel(
    const float* __restrict__ v,
    const int*   __restrict__ src,
    const int*   __restrict__ dst,
    const float* __restrict__ t1,
    const float* __restrict__ t2,
    const float* __restrict__ cond,
    float*       __restrict__ partial,   // PRIV: [8][N]; else: out [N]
    int N, int E)
{
    float* my = PRIV ? (partial + (size_t)xcc_id() * N) : partial;

    const int E4 = E & ~3;
    int chunk = blockIdx.x * blockDim.x + threadIdx.x;
    int nthreads = gridDim.x * blockDim.x;

    for (int i = chunk * 4; i + 3 < E4; i += nthreads * 4) {
        int4   s4 = *(const int4*)  (src  + i);
        int4   d4 = *(const int4*)  (dst  + i);
        float4 a4 = *(const float4*)(t1   + i);
        float4 b4 = *(const float4*)(t2   + i);
        float4 c4 = *(const float4*)(cond + i);

        float x0 = fmaf(a4.x, v[s4.x] - v[d4.x], b4.x);
        float x1 = fmaf(a4.y, v[s4.y] - v[d4.y], b4.y);
        float x2 = fmaf(a4.z, v[s4.z] - v[d4.z], b4.z);
        float x3 = fmaf(a4.w, v[s4.w] - v[d4.w], b4.w);

        if (PRIV) {
            if (x0 > 0.0f) { float c = c4.x * x0; atom_add_local(&my[d4.x],  c); atom_add_local(&my[s4.x], -c); }
            if (x1 > 0.0f) { float c = c4.y * x1; atom_add_local(&my[d4.y],  c); atom_add_local(&my[s4.y], -c); }
            if (x2 > 0.0f) { float c = c4.z * x2; atom_add_local(&my[d4.z],  c); atom_add_local(&my[s4.z], -c); }
            if (x3 > 0.0f) { float c = c4.w * x3; atom_add_local(&my[d4.w],  c); atom_add_local(&my[s4.w], -c); }
        } else {
            if (x0 > 0.0f) { float c = c4.x * x0; atomicAdd(&my[d4.x],  c); atomicAdd(&my[s4.x], -c); }
            if (x1 > 0.0f) { float c = c4.y * x1; atomicAdd(&my[d4.y],  c); atomicAdd(&my[s4.y], -c); }
            if (x2 > 0.0f) { float c = c4.z * x2; atomicAdd(&my[d4.z],  c); atomicAdd(&my[s4.z], -c); }
            if (x3 > 0.0f) { float c = c4.w * x3; atomicAdd(&my[d4.w],  c); atomicAdd(&my[s4.w], -c); }
        }
    }

    for (int i = E4 + chunk; i < E; i += nthreads) {
        int s = src[i], d = dst[i];
        float x = fmaf(t1[i], v[s] - v[d], t2[i]);
        if (x > 0.0f) {
            float c = cond[i] * x;
            if (PRIV) { atom_add_local(&my[d], c); atom_add_local(&my[s], -c); }
            else      { atomicAdd(&my[d], c);      atomicAdd(&my[s], -c); }
        }
    }
}

__global__ __launch_bounds__(256) void kirchhoff_reduce_kernel(
    const float* __restrict__ partial, float* __restrict__ out, int N4)
{
    // N4 = N/4 float4 elements per copy; sums 8 copies
    int n = blockIdx.x * blockDim.x + threadIdx.x;
    if (n < N4) {
        float4 s = make_float4(0.f, 0.f, 0.f, 0.f);
        for (int p = 0; p < 8; ++p) {
            float4 q = ((const float4*)partial)[(size_t)p * N4 + n];
            s.x += q.x; s.y += q.y; s.z += q.z; s.w += q.w;
        }
        ((float4*)out)[n] = s;
    }
}

__global__ __launch_bounds__(256) void kirchhoff_reduce_scalar_kernel(
    const float* __restrict__ partial, float* __restrict__ out, int N)
{
    int n = blockIdx.x * blockDim.x + threadIdx.x;
    if (n < N) {
        float s = 0.0f;
        for (int p = 0; p < 8; ++p) s += partial[(size_t)p * N + n];
        out[n] = s;
    }
}

extern "C" void kernel_launch(void* const* d_in, const int* in_sizes, int n_in,
                              void* d_out, int out_size, void* d_ws, size_t ws_size,
                              hipStream_t stream) {
    const float* v    = (const float*)d_in[1];
    const int*   src  = (const int*)  d_in[2];
    const int*   dst  = (const int*)  d_in[3];
    const float* t1   = (const float*)d_in[4];
    const float* t2   = (const float*)d_in[5];
    const float* cond = (const float*)d_in[6];
    float* out = (float*)d_out;
    const int E = in_sizes[2];
    const int N = out_size;

    const size_t per = (size_t)N * sizeof(float);
    const bool priv = (ws_size >= 8 * per);

    const int block = 256;
    int chunks = (E + 3) / 4;
    int grid = (chunks + block - 1) / block;

    if (priv) {
        float* partial = (float*)d_ws;
        hipMemsetAsync(partial, 0, 8 * per, stream);
        kirchhoff_edge_kernel<true><<<grid, block, 0, stream>>>(v, src, dst, t1, t2, cond,
                                                                partial, N, E);
        if ((N & 3) == 0) {
            int n4 = N / 4;
            kirchhoff_reduce_kernel<<<(n4 + block - 1) / block, block, 0, stream>>>(partial, out, n4);
        } else {
            kirchhoff_reduce_scalar_kernel<<<(N + block - 1) / block, block, 0, stream>>>(partial, out, N);
        }
    } else {
        hipMemsetAsync(out, 0, per, stream);
        kirchhoff_edge_kernel<false><<<grid, block, 0, stream>>>(v, src, dst, t1, t2, cond,
                                                                 out, N, E);
    }
}

// Round 4
// 85.640 us; speedup vs baseline: 2.0807x; 2.0178x over previous
//
#include <hip/hip_runtime.h>

// KirchhoffNet: out[n] = sum_{dst==n} cur - sum_{src==n} cur,
// cur = cond * relu(t1*(v[src]-v[dst]) + t2)
//
// Round 4: global fp32 atomics write through to HBM at 32B/op on this chip
// (WRITE_SIZE == atomics*32B across 3 structurally different kernels; 617 GB/s
// scattered-32B ceiling == measured dur). So: NO global atomics. Pass 0
// precomputes per-edge currents (dense). Pass 1 tiles nodes into 16K ranges
// held in LDS (64KB fp32), accumulates via LDS atomics, flushes with plain
// dense stores into per-slice partials. Pass 2 reduces partials.

#define RANGE   16384
#define P1_BLK  512

__global__ __launch_bounds__(256) void edge_current_kernel(
    const float* __restrict__ v,
    const int*   __restrict__ src,
    const int*   __restrict__ dst,
    const float* __restrict__ t1,
    const float* __restrict__ t2,
    const float* __restrict__ cond,
    float*       __restrict__ cur,
    int E)
{
    const int E4 = E & ~3;
    int i = (blockIdx.x * blockDim.x + threadIdx.x) * 4;
    int stride = gridDim.x * blockDim.x * 4;
    for (; i < E4; i += stride) {
        int4   s4 = *(const int4*)  (src  + i);
        int4   d4 = *(const int4*)  (dst  + i);
        float4 a4 = *(const float4*)(t1   + i);
        float4 b4 = *(const float4*)(t2   + i);
        float4 c4 = *(const float4*)(cond + i);
        float4 o;
        float x0 = fmaf(a4.x, v[s4.x] - v[d4.x], b4.x);
        float x1 = fmaf(a4.y, v[s4.y] - v[d4.y], b4.y);
        float x2 = fmaf(a4.z, v[s4.z] - v[d4.z], b4.z);
        float x3 = fmaf(a4.w, v[s4.w] - v[d4.w], b4.w);
        o.x = x0 > 0.0f ? c4.x * x0 : 0.0f;
        o.y = x1 > 0.0f ? c4.y * x1 : 0.0f;
        o.z = x2 > 0.0f ? c4.z * x2 : 0.0f;
        o.w = x3 > 0.0f ? c4.w * x3 : 0.0f;
        *(float4*)(cur + i) = o;
    }
    // scalar tail
    int t = E4 + blockIdx.x * blockDim.x + threadIdx.x;
    if (t < E) {
        float x = fmaf(t1[t], v[src[t]] - v[dst[t]], t2[t]);
        cur[t] = x > 0.0f ? cond[t] * x : 0.0f;
    }
}

__global__ __launch_bounds__(P1_BLK) void range_accum_kernel(
    const int*   __restrict__ src,
    const int*   __restrict__ dst,
    const float* __restrict__ cur,
    float*       __restrict__ partial,   // [B][N]
    int N, int E, int B, int sliceLen)
{
    __shared__ __align__(16) float acc[RANGE];

    const int b    = blockIdx.x % B;
    const int r    = blockIdx.x / B;
    const int base = r * RANGE;
    const int len  = min(RANGE, N - base);

    for (int i = threadIdx.x; i < RANGE; i += P1_BLK) acc[i] = 0.0f;
    __syncthreads();

    const int E4 = E & ~3;
    const int s0 = b * sliceLen;
    const int s1 = min(s0 + sliceLen, E4);

    for (int i = s0 + threadIdx.x * 4; i < s1; i += P1_BLK * 4) {
        int4   ss = *(const int4*)  (src + i);
        int4   dd = *(const int4*)  (dst + i);
        float4 cc = *(const float4*)(cur + i);
        #define PROC(S, D, C)                                              \
            if ((C) != 0.0f) {                                             \
                unsigned du = (unsigned)((D) - base);                      \
                if (du < (unsigned)len) atomicAdd(&acc[du],  (C));         \
                unsigned su = (unsigned)((S) - base);                      \
                if (su < (unsigned)len) atomicAdd(&acc[su], -(C));         \
            }
        PROC(ss.x, dd.x, cc.x)
        PROC(ss.y, dd.y, cc.y)
        PROC(ss.z, dd.z, cc.z)
        PROC(ss.w, dd.w, cc.w)
    }
    // tail edges (E not multiple of 4): handled once, by slice b==B-1 blocks
    if (b == B - 1) {
        for (int i = E4 + threadIdx.x; i < E; i += P1_BLK) {
            float c = cur[i];
            PROC(src[i], dst[i], c)
        }
        #undef PROC
    }

    __syncthreads();
    // dense flush: plain stores, no atomics
    float* outp = partial + (size_t)b * N + base;
    const int len4 = len & ~3;
    for (int i = threadIdx.x * 4; i < len4; i += P1_BLK * 4)
        *(float4*)(outp + i) = *(const float4*)&acc[i];
    for (int i = len4 + threadIdx.x; i < len; i += P1_BLK)
        outp[i] = acc[i];
}

__global__ __launch_bounds__(256) void reduce_kernel(
    const float* __restrict__ partial, float* __restrict__ out, int N4, int B)
{
    int n = blockIdx.x * blockDim.x + threadIdx.x;
    if (n < N4) {
        float4 s = make_float4(0.f, 0.f, 0.f, 0.f);
        for (int p = 0; p < B; ++p) {
            float4 q = ((const float4*)partial)[(size_t)p * N4 + n];
            s.x += q.x; s.y += q.y; s.z += q.z; s.w += q.w;
        }
        ((float4*)out)[n] = s;
    }
}

// fallback: direct global atomics (slow but correct) if ws is too small
__global__ __launch_bounds__(256) void atomic_fallback_kernel(
    const float* __restrict__ v, const int* __restrict__ src, const int* __restrict__ dst,
    const float* __restrict__ t1, const float* __restrict__ t2, const float* __restrict__ cond,
    float* __restrict__ out, int E)
{
    int i = blockIdx.x * blockDim.x + threadIdx.x;
    int stride = gridDim.x * blockDim.x;
    for (; i < E; i += stride) {
        int s = src[i], d = dst[i];
        float x = fmaf(t1[i], v[s] - v[d], t2[i]);
        if (x > 0.0f) {
            float c = cond[i] * x;
            atomicAdd(&out[d], c);
            atomicAdd(&out[s], -c);
        }
    }
}

extern "C" void kernel_launch(void* const* d_in, const int* in_sizes, int n_in,
                              void* d_out, int out_size, void* d_ws, size_t ws_size,
                              hipStream_t stream) {
    // inputs: t(0), v(1), src(2), dst(3), theta_sd_1(4), theta_sd_2(5), conductance(6)
    const float* v    = (const float*)d_in[1];
    const int*   src  = (const int*)  d_in[2];
    const int*   dst  = (const int*)  d_in[3];
    const float* t1   = (const float*)d_in[4];
    const float* t2   = (const float*)d_in[5];
    const float* cond = (const float*)d_in[6];
    float* out = (float*)d_out;
    const int E = in_sizes[2];
    const int N = out_size;

    const size_t curBytes = (((size_t)E * sizeof(float)) + 255) & ~(size_t)255;
    const size_t perCopy  = (size_t)N * sizeof(float);

    int B = 0;
    const int cands[] = {64, 48, 32, 24, 16, 12, 8};
    for (int c : cands) {
        if (curBytes + (size_t)c * perCopy <= ws_size) { B = c; break; }
    }

    if (B > 0 && (N & 3) == 0) {
        float* cur     = (float*)d_ws;
        float* partial = (float*)((char*)d_ws + curBytes);

        const int E4 = E & ~3;
        int chunks = (E4 + 3) / 4;
        int g0 = (chunks + 255) / 256;
        if (g0 < 1) g0 = 1;
        edge_current_kernel<<<g0, 256, 0, stream>>>(v, src, dst, t1, t2, cond, cur, E);

        const int R = (N + RANGE - 1) / RANGE;
        int sliceLen = ((E4 + B - 1) / B + 3) & ~3;
        range_accum_kernel<<<R * B, P1_BLK, 0, stream>>>(src, dst, cur, partial,
                                                         N, E, B, sliceLen);

        int n4 = N / 4;
        reduce_kernel<<<(n4 + 255) / 256, 256, 0, stream>>>(partial, out, n4, B);
    } else {
        hipMemsetAsync(out, 0, perCopy, stream);
        int grid = (E + 255) / 256;
        if (grid > 2048) grid = 2048;
        atomic_fallback_kernel<<<grid, 256, 0, stream>>>(v, src, dst, t1, t2, cond, out, E);
    }
}